// Round 1
// baseline (1074.804 us; speedup 1.0000x reference)
//
#include <hip/hip_runtime.h>
#include <stdint.h>

#define B_ 4
#define NH_ 4
#define T_ 512
#define D_ 256
#define N_ 8192
#define SCALE_ 0.011048543456039806f   // 8192^-0.5

typedef __attribute__((ext_vector_type(8))) short bf16x8;
typedef __attribute__((ext_vector_type(4))) float f32x4;

__device__ __forceinline__ unsigned short f2bf(float x) {
  union { float f; unsigned u; } v; v.f = x;
  unsigned r = v.u + 0x7fffu + ((v.u >> 16) & 1u);   // RNE
  return (unsigned short)(r >> 16);
}

// ---------------- Kernel 1: QR = rope(Q) -> bf16 ----------------
__global__ __launch_bounds__(256) void rope_kernel(
    const float* __restrict__ Q, const float* __restrict__ Cos,
    const float* __restrict__ Sin, unsigned short* __restrict__ QR)
{
  size_t i8 = ((size_t)blockIdx.x * 256 + threadIdx.x) * 8;
  int t = (int)((i8 >> 13) & (T_ - 1));   // N_ = 2^13, T_ = 2^9
  int n = (int)(i8 & (N_ - 1));
  const float4 q0 = *(const float4*)(Q + i8);
  const float4 q1 = *(const float4*)(Q + i8 + 4);
  const float* cp = Cos + (size_t)t * N_ + n;
  const float* sp = Sin + (size_t)t * N_ + n;
  float4 c0 = *(const float4*)cp, c1 = *(const float4*)(cp + 4);
  float4 s0 = *(const float4*)sp, s1 = *(const float4*)(sp + 4);
  // qr[2i] = q[2i]*cos[2i] - q[2i+1]*sin[2i]; qr[2i+1] = q[2i+1]*cos[2i+1] + q[2i]*sin[2i+1]
  __attribute__((aligned(16))) unsigned short u[8];
  u[0] = f2bf(q0.x * c0.x - q0.y * s0.x);
  u[1] = f2bf(q0.y * c0.y + q0.x * s0.y);
  u[2] = f2bf(q0.z * c0.z - q0.w * s0.z);
  u[3] = f2bf(q0.w * c0.w + q0.z * s0.w);
  u[4] = f2bf(q1.x * c1.x - q1.y * s1.x);
  u[5] = f2bf(q1.y * c1.y + q1.x * s1.y);
  u[6] = f2bf(q1.z * c1.z - q1.w * s1.z);
  u[7] = f2bf(q1.w * c1.w + q1.z * s1.w);
  *(uint4*)(QR + i8) = *(const uint4*)u;
}

// ------- Kernel 2: scores = mask(QR @ QR^T) * SCALE -> bf16 -------
// 64x64 C-tile per block, 4 waves, each wave = 16x64 (4 x 16x16x32 MFMA)
__global__ __launch_bounds__(256) void scores_kernel(
    const unsigned short* __restrict__ QR, unsigned short* __restrict__ Sc)
{
  const int bh = blockIdx.z;
  const int i0 = blockIdx.y * 64, j0 = blockIdx.x * 64;
  unsigned short* outp = Sc + (size_t)bh * T_ * T_;
  const int tid = threadIdx.x;
  if (blockIdx.x > blockIdx.y) {       // strictly-upper tile: all masked -> zero-fill
    const int r = tid >> 2, cb = (tid & 3) * 16;
    uint4 z = make_uint4(0u, 0u, 0u, 0u);
    unsigned short* p = outp + (size_t)(i0 + r) * T_ + j0 + cb;
    *(uint4*)p = z;
    *(uint4*)(p + 8) = z;
    return;
  }
  const unsigned short* A = QR + (size_t)bh * T_ * N_;
  __shared__ unsigned short as[64 * 40];   // 64 rows x 32 bf16, +8 pad (rows 80B, 16B-aligned)
  __shared__ unsigned short bs[64 * 40];
  const int lane = tid & 63, w = tid >> 6;
  const int q = lane >> 4, cl = lane & 15;
  const int lrow = tid >> 2, lcol = (tid & 3) * 8;
  f32x4 acc[4];
  #pragma unroll
  for (int c = 0; c < 4; c++) acc[c] = (f32x4){0.f, 0.f, 0.f, 0.f};
  for (int k0 = 0; k0 < N_; k0 += 32) {
    uint4 va = *(const uint4*)(A + (size_t)(i0 + lrow) * N_ + k0 + lcol);
    uint4 vb = *(const uint4*)(A + (size_t)(j0 + lrow) * N_ + k0 + lcol);
    *(uint4*)(as + lrow * 40 + lcol) = va;
    *(uint4*)(bs + lrow * 40 + lcol) = vb;
    __syncthreads();
    bf16x8 af = *(const bf16x8*)(as + (w * 16 + cl) * 40 + q * 8);
    #pragma unroll
    for (int c = 0; c < 4; c++) {
      bf16x8 bfr = *(const bf16x8*)(bs + (c * 16 + cl) * 40 + q * 8);
      acc[c] = __builtin_amdgcn_mfma_f32_16x16x32_bf16(af, bfr, acc[c], 0, 0, 0);
    }
    __syncthreads();
  }
  #pragma unroll
  for (int c = 0; c < 4; c++) {
    #pragma unroll
    for (int r = 0; r < 4; r++) {
      int gi = i0 + w * 16 + q * 4 + r;   // C/D: row=(lane>>4)*4+reg, col=lane&15
      int gj = j0 + c * 16 + cl;
      float v = (gj < gi) ? acc[c][r] * SCALE_ : 0.f;   // tril(k=-1)
      outp[(size_t)gi * T_ + gj] = f2bf(v);
    }
  }
}

// ------- Kernel 3: out = scores @ V + QR @ state (fp32 out) -------
__global__ __launch_bounds__(256) void out_kernel(
    const unsigned short* __restrict__ QR, const unsigned short* __restrict__ Sc,
    const float* __restrict__ V, const float* __restrict__ state,
    float* __restrict__ Out)
{
  const int bh = blockIdx.z, b = bh >> 2;
  const int i0 = blockIdx.y * 64, n0 = blockIdx.x * 64;
  const unsigned short* Aq = QR + (size_t)bh * T_ * N_;
  const unsigned short* As = Sc + (size_t)bh * T_ * T_;
  const float* Bst = state + (size_t)bh * N_ * D_;
  const float* Bv  = V + (size_t)b * T_ * D_;
  const int tid = threadIdx.x, lane = tid & 63, w = tid >> 6;
  const int q = lane >> 4, cl = lane & 15;
  const int arow = tid >> 2, acol = (tid & 3) * 8;  // A staging: 64x32 row-major
  const int bn = tid & 63, bkb = (tid >> 6) * 8;    // B staging: column strip (transpose)
  __shared__ unsigned short as[64 * 40];
  __shared__ unsigned short bs[64 * 40];            // bs[n][k] (B^T layout)
  f32x4 acc[4];
  #pragma unroll
  for (int c = 0; c < 4; c++) acc[c] = (f32x4){0.f, 0.f, 0.f, 0.f};

  // phase 1: QR @ state, K = 8192 (B fp32 -> bf16 on the fly)
  for (int k0 = 0; k0 < N_; k0 += 32) {
    uint4 va = *(const uint4*)(Aq + (size_t)(i0 + arow) * N_ + k0 + acol);
    float fb[8];
    #pragma unroll
    for (int j = 0; j < 8; j++)
      fb[j] = Bst[(size_t)(k0 + bkb + j) * D_ + n0 + bn];  // coalesced per j
    *(uint4*)(as + arow * 40 + acol) = va;
    __attribute__((aligned(16))) unsigned short ub[8];
    #pragma unroll
    for (int j = 0; j < 8; j++) ub[j] = f2bf(fb[j]);
    *(uint4*)(bs + bn * 40 + bkb) = *(const uint4*)ub;     // one b128 write
    __syncthreads();
    bf16x8 af = *(const bf16x8*)(as + (w * 16 + cl) * 40 + q * 8);
    #pragma unroll
    for (int c = 0; c < 4; c++) {
      bf16x8 bfr = *(const bf16x8*)(bs + (c * 16 + cl) * 40 + q * 8);
      acc[c] = __builtin_amdgcn_mfma_f32_16x16x32_bf16(af, bfr, acc[c], 0, 0, 0);
    }
    __syncthreads();
  }
  // phase 2: scores @ V, K = 512
  for (int k0 = 0; k0 < T_; k0 += 32) {
    uint4 va = *(const uint4*)(As + (size_t)(i0 + arow) * T_ + k0 + acol);
    float fb[8];
    #pragma unroll
    for (int j = 0; j < 8; j++)
      fb[j] = Bv[(size_t)(k0 + bkb + j) * D_ + n0 + bn];
    *(uint4*)(as + arow * 40 + acol) = va;
    __attribute__((aligned(16))) unsigned short ub[8];
    #pragma unroll
    for (int j = 0; j < 8; j++) ub[j] = f2bf(fb[j]);
    *(uint4*)(bs + bn * 40 + bkb) = *(const uint4*)ub;
    __syncthreads();
    bf16x8 af = *(const bf16x8*)(as + (w * 16 + cl) * 40 + q * 8);
    #pragma unroll
    for (int c = 0; c < 4; c++) {
      bf16x8 bfr = *(const bf16x8*)(bs + (c * 16 + cl) * 40 + q * 8);
      acc[c] = __builtin_amdgcn_mfma_f32_16x16x32_bf16(af, bfr, acc[c], 0, 0, 0);
    }
    __syncthreads();
  }
  float* op = Out + (size_t)bh * T_ * D_;
  #pragma unroll
  for (int c = 0; c < 4; c++) {
    #pragma unroll
    for (int r = 0; r < 4; r++) {
      int gi = i0 + w * 16 + q * 4 + r;
      int gj = n0 + c * 16 + cl;
      op[(size_t)gi * D_ + gj] = acc[c][r];
    }
  }
}

// ------- Kernel 4: new_state = state + SCALE * QR^T @ V -------
__global__ __launch_bounds__(256) void nstate_kernel(
    const unsigned short* __restrict__ QR, const float* __restrict__ V,
    const float* __restrict__ state, float* __restrict__ Out)
{
  const int bh = blockIdx.z, b = bh >> 2;
  const int m0 = blockIdx.y * 64, n0 = blockIdx.x * 64;
  const unsigned short* Aq = QR + (size_t)bh * T_ * N_;
  const float* Bv = V + (size_t)b * T_ * D_;
  const float* St = state + (size_t)bh * N_ * D_;
  const int tid = threadIdx.x, lane = tid & 63, w = tid >> 6;
  const int q = lane >> 4, cl = lane & 15;
  const int cn = tid & 63, kb = (tid >> 6) * 8;   // column strip for A^T and B
  __shared__ unsigned short as[64 * 40];          // as[m][k] = QR[k][m]
  __shared__ unsigned short bs[64 * 40];          // bs[n][k] = V[k][n]
  f32x4 acc[4];
  #pragma unroll
  for (int c = 0; c < 4; c++) acc[c] = (f32x4){0.f, 0.f, 0.f, 0.f};
  for (int k0 = 0; k0 < T_; k0 += 32) {
    __attribute__((aligned(16))) unsigned short ua[8];
    float fb[8];
    #pragma unroll
    for (int j = 0; j < 8; j++) {
      ua[j] = Aq[(size_t)(k0 + kb + j) * N_ + m0 + cn];     // coalesced per j
      fb[j] = Bv[(size_t)(k0 + kb + j) * D_ + n0 + cn];
    }
    __attribute__((aligned(16))) unsigned short ub[8];
    #pragma unroll
    for (int j = 0; j < 8; j++) ub[j] = f2bf(fb[j]);
    *(uint4*)(as + cn * 40 + kb) = *(const uint4*)ua;
    *(uint4*)(bs + cn * 40 + kb) = *(const uint4*)ub;
    __syncthreads();
    bf16x8 af = *(const bf16x8*)(as + (w * 16 + cl) * 40 + q * 8);
    #pragma unroll
    for (int c = 0; c < 4; c++) {
      bf16x8 bfr = *(const bf16x8*)(bs + (c * 16 + cl) * 40 + q * 8);
      acc[c] = __builtin_amdgcn_mfma_f32_16x16x32_bf16(af, bfr, acc[c], 0, 0, 0);
    }
    __syncthreads();
  }
  float* op = Out + (size_t)(B_ * NH_ * T_ * D_) + (size_t)bh * N_ * D_;
  #pragma unroll
  for (int c = 0; c < 4; c++) {
    #pragma unroll
    for (int r = 0; r < 4; r++) {
      int gm = m0 + w * 16 + q * 4 + r;
      int gn = n0 + c * 16 + cl;
      size_t off = (size_t)gm * D_ + gn;
      op[off] = St[off] + SCALE_ * acc[c][r];
    }
  }
}

extern "C" void kernel_launch(void* const* d_in, const int* in_sizes, int n_in,
                              void* d_out, int out_size, void* d_ws, size_t ws_size,
                              hipStream_t stream) {
  const float* Q     = (const float*)d_in[0];
  const float* V     = (const float*)d_in[1];
  const float* state = (const float*)d_in[2];
  const float* Cos   = (const float*)d_in[3];
  const float* Sin   = (const float*)d_in[4];
  float* out = (float*)d_out;

  // ws layout: QR bf16 (B*NH*T*N = 67,108,864 elts, 128 MiB) | scores bf16 (4,194,304 elts, 8 MiB)
  unsigned short* QR = (unsigned short*)d_ws;
  unsigned short* Sc = QR + (size_t)B_ * NH_ * T_ * N_;

  // 1) RoPE + cast: 67,108,864 elems / 8 per thread / 256 per block
  rope_kernel<<<dim3(32768), dim3(256), 0, stream>>>(Q, Cos, Sin, QR);
  // 2) scores: 8x8 64-tiles per head, 16 heads
  scores_kernel<<<dim3(8, 8, B_ * NH_), dim3(256), 0, stream>>>(QR, Sc);
  // 3) out: 4x8 tiles per head
  out_kernel<<<dim3(4, 8, B_ * NH_), dim3(256), 0, stream>>>(QR, Sc, V, state, out);
  // 4) new_state: 4x128 tiles per head
  nstate_kernel<<<dim3(4, 128, B_ * NH_), dim3(256), 0, stream>>>(QR, V, state, out);
}

// Round 2
// 864.845 us; speedup vs baseline: 1.2428x; 1.2428x over previous
//
#include <hip/hip_runtime.h>
#include <stdint.h>

#define B_ 4
#define NH_ 4
#define T_ 512
#define D_ 256
#define N_ 8192
#define NHEAD 16
#define SCALE_ 0.011048543456039806f   // 8192^-0.5

typedef __attribute__((ext_vector_type(8))) short bf16x8;
typedef __attribute__((ext_vector_type(4))) float f32x4;

__device__ __forceinline__ unsigned short f2bf(float x) {
  union { float f; unsigned u; } v; v.f = x;
  unsigned r = v.u + 0x7fffu + ((v.u >> 16) & 1u);   // RNE
  return (unsigned short)(r >> 16);
}

// async global->LDS, 16B per lane. LDS dest must be wave-uniform base + lane*16.
__device__ __forceinline__ void async16(const void* g, void* l) {
  __builtin_amdgcn_global_load_lds(
      (const __attribute__((address_space(1))) unsigned int*)g,
      (__attribute__((address_space(3))) unsigned int*)l,
      16, 0, 0);
}

// Stage a 128x32 bf16 tile from row-major source (pre-offset to r0,k0), ld in elems.
// LDS layout [128][32] (64B rows, linear -> lane l of wave w writes bytes w*1024+l*16). 
__device__ __forceinline__ void stage_direct(const unsigned short* __restrict__ g,
                                             int ld, unsigned short* lds, int t) {
  const int row = t >> 2, c8 = (t & 3) * 8;
  async16(g + (size_t)row * ld + c8, lds + row * 32 + c8);
  async16(g + (size_t)(row + 64) * ld + c8, lds + (row + 64) * 32 + c8);
}

// Stage a 128(m) x 32(k) bf16 tile from K-MAJOR source g[(k)*ld + m] (pre-offset to k0,m0).
// LDS layout [128][40] padded (80B rows -> 2-way bank aliasing on b128 = free).
__device__ __forceinline__ void stage_trans_bf16(const unsigned short* __restrict__ g,
                                                 int ld, unsigned short* lds, int t) {
  const int mn = t & 127, ks = (t >> 7) * 16;
  __attribute__((aligned(16))) unsigned short u[16];
  #pragma unroll
  for (int i = 0; i < 16; i++) u[i] = g[(size_t)(ks + i) * ld + mn];  // lanes: consecutive mn -> coalesced
  *(uint4*)(lds + mn * 40 + ks)     = *(const uint4*)u;
  *(uint4*)(lds + mn * 40 + ks + 8) = *(const uint4*)(u + 8);
}

// Same but fp32 source with on-the-fly bf16 cast.
__device__ __forceinline__ void stage_trans_f32(const float* __restrict__ g,
                                                int ld, unsigned short* lds, int t) {
  const int mn = t & 127, ks = (t >> 7) * 16;
  float f[16];
  #pragma unroll
  for (int i = 0; i < 16; i++) f[i] = g[(size_t)(ks + i) * ld + mn];
  __attribute__((aligned(16))) unsigned short u[16];
  #pragma unroll
  for (int i = 0; i < 16; i++) u[i] = f2bf(f[i]);
  *(uint4*)(lds + mn * 40 + ks)     = *(const uint4*)u;
  *(uint4*)(lds + mn * 40 + ks + 8) = *(const uint4*)(u + 8);
}

// One BK=32 step: 8 ds_read_b128 + 16 MFMA per wave. Wave (wr,wc) covers 64x64 of the 128x128 C.
__device__ __forceinline__ void mfma_step(const unsigned short* as, int lda,
                                          const unsigned short* bs, int ldb,
                                          int wr, int wc, int lane, f32x4 acc[4][4]) {
  const int q8 = (lane >> 4) * 8, rl = lane & 15;
  bf16x8 a[4], b[4];
  #pragma unroll
  for (int i = 0; i < 4; i++)
    a[i] = *(const bf16x8*)(as + (wr * 64 + i * 16 + rl) * lda + q8);
  #pragma unroll
  for (int j = 0; j < 4; j++)
    b[j] = *(const bf16x8*)(bs + (wc * 64 + j * 16 + rl) * ldb + q8);
  #pragma unroll
  for (int i = 0; i < 4; i++)
    #pragma unroll
    for (int j = 0; j < 4; j++)
      acc[i][j] = __builtin_amdgcn_mfma_f32_16x16x32_bf16(a[i], b[j], acc[i][j], 0, 0, 0);
}

// ---------------- Kernel 1: QR = rope(Q) -> bf16 ----------------
__global__ __launch_bounds__(256) void rope_kernel(
    const float* __restrict__ Q, const float* __restrict__ Cos,
    const float* __restrict__ Sin, unsigned short* __restrict__ QR)
{
  size_t i8 = ((size_t)blockIdx.x * 256 + threadIdx.x) * 8;
  int t = (int)((i8 >> 13) & (T_ - 1));
  int n = (int)(i8 & (N_ - 1));
  const float4 q0 = *(const float4*)(Q + i8);
  const float4 q1 = *(const float4*)(Q + i8 + 4);
  const float* cp = Cos + (size_t)t * N_ + n;
  const float* sp = Sin + (size_t)t * N_ + n;
  float4 c0 = *(const float4*)cp, c1 = *(const float4*)(cp + 4);
  float4 s0 = *(const float4*)sp, s1 = *(const float4*)(sp + 4);
  __attribute__((aligned(16))) unsigned short u[8];
  u[0] = f2bf(q0.x * c0.x - q0.y * s0.x);
  u[1] = f2bf(q0.y * c0.y + q0.x * s0.y);
  u[2] = f2bf(q0.z * c0.z - q0.w * s0.z);
  u[3] = f2bf(q0.w * c0.w + q0.z * s0.w);
  u[4] = f2bf(q1.x * c1.x - q1.y * s1.x);
  u[5] = f2bf(q1.y * c1.y + q1.x * s1.y);
  u[6] = f2bf(q1.z * c1.z - q1.w * s1.z);
  u[7] = f2bf(q1.w * c1.w + q1.z * s1.w);
  *(uint4*)(QR + i8) = *(const uint4*)u;
}

// ---------------- Kernel 2 (mega): scores + QR@state + new_state + zerofill ----------------
// block roles (heavy first so they dispatch early):
//   [0,160)      scores 128x128 lower-tri tiles, K=8192
//   [160,288)    out_p1 = QR@state, 128x128 tiles, K=8192
//   [288,2336)   nstate = state + SCALE*QR^T@V, 128x128 tiles, K=512
//   [2336,2432)  scores upper-tile zero fill
#define NB_SC 160
#define NB_OP 128
#define NB_NS 2048
#define OUT_STATE_OFF ((size_t)NHEAD * T_ * D_)

__global__ __launch_bounds__(256) void mega_kernel(
    const unsigned short* __restrict__ QR, const float* __restrict__ V,
    const float* __restrict__ state, unsigned short* __restrict__ Sc,
    float* __restrict__ Out)
{
  __shared__ unsigned short as[128 * 40];
  __shared__ unsigned short bs[128 * 40];
  const int blk = blockIdx.x, t = threadIdx.x;
  const int lane = t & 63, w = t >> 6, wr = w >> 1, wc = w & 1;
  const int q4 = (lane >> 4) * 4, rl = lane & 15;
  f32x4 acc[4][4];
  #pragma unroll
  for (int i = 0; i < 4; i++)
    #pragma unroll
    for (int j = 0; j < 4; j++) acc[i][j] = (f32x4){0.f, 0.f, 0.f, 0.f};

  if (blk < NB_SC) {
    // ---- scores = tril_{-1}(QR QR^T)*SCALE -> bf16
    static const int TI[10] = {0,1,1,2,2,2,3,3,3,3};
    static const int TJ[10] = {0,0,1,0,1,2,0,1,2,3};
    const int head = blk / 10, ti = TI[blk % 10], tj = TJ[blk % 10];
    const unsigned short* A  = QR + (size_t)head * T_ * N_ + (size_t)ti * 128 * N_;
    const unsigned short* Bp = QR + (size_t)head * T_ * N_ + (size_t)tj * 128 * N_;
    for (int k0 = 0; k0 < N_; k0 += 32) {
      stage_direct(A + k0, N_, as, t);
      stage_direct(Bp + k0, N_, bs, t);
      __syncthreads();
      mfma_step(as, 32, bs, 32, wr, wc, lane, acc);
      __syncthreads();
    }
    unsigned short* op = Sc + (size_t)head * T_ * T_;
    const bool diag = (ti == tj);
    #pragma unroll
    for (int i = 0; i < 4; i++)
      #pragma unroll
      for (int j = 0; j < 4; j++)
        #pragma unroll
        for (int r = 0; r < 4; r++) {
          int gi = ti * 128 + wr * 64 + i * 16 + q4 + r;
          int gj = tj * 128 + wc * 64 + j * 16 + rl;
          float v = acc[i][j][r] * SCALE_;
          if (diag && gj >= gi) v = 0.f;
          op[(size_t)gi * T_ + gj] = f2bf(v);
        }
  } else if (blk < NB_SC + NB_OP) {
    // ---- out partial = QR @ state (fp32 to d_out; Sc@V added by final kernel)
    const int idx = blk - NB_SC;
    const int head = idx >> 3, mt = (idx & 7) >> 1, nt = idx & 1;
    const unsigned short* A = QR + (size_t)head * T_ * N_ + (size_t)mt * 128 * N_;
    const float* Bp = state + (size_t)head * N_ * D_ + nt * 128;   // K-major [n][d]
    for (int k0 = 0; k0 < N_; k0 += 32) {
      stage_direct(A + k0, N_, as, t);
      stage_trans_f32(Bp + (size_t)k0 * D_, D_, bs, t);
      __syncthreads();
      mfma_step(as, 32, bs, 40, wr, wc, lane, acc);
      __syncthreads();
    }
    float* op = Out + (size_t)head * T_ * D_;
    #pragma unroll
    for (int i = 0; i < 4; i++)
      #pragma unroll
      for (int j = 0; j < 4; j++)
        #pragma unroll
        for (int r = 0; r < 4; r++) {
          int gi = mt * 128 + wr * 64 + i * 16 + q4 + r;
          int gj = nt * 128 + wc * 64 + j * 16 + rl;
          op[(size_t)gi * D_ + gj] = acc[i][j][r];
        }
  } else if (blk < NB_SC + NB_OP + NB_NS) {
    // ---- new_state = state + SCALE * QR^T @ V
    const int idx = blk - (NB_SC + NB_OP);
    const int head = idx >> 7, mt = (idx & 127) >> 1, nt = idx & 1;
    const unsigned short* Asrc = QR + (size_t)head * T_ * N_ + mt * 128;  // K-major [t][n]
    const float* Bp = V + (size_t)(head >> 2) * T_ * D_ + nt * 128;       // K-major [t][d]
    for (int k0 = 0; k0 < T_; k0 += 32) {
      stage_trans_bf16(Asrc + (size_t)k0 * N_, N_, as, t);
      stage_trans_f32(Bp + (size_t)k0 * D_, D_, bs, t);
      __syncthreads();
      mfma_step(as, 40, bs, 40, wr, wc, lane, acc);
      __syncthreads();
    }
    const float* st = state + (size_t)head * N_ * D_;
    float* op = Out + OUT_STATE_OFF + (size_t)head * N_ * D_;
    #pragma unroll
    for (int i = 0; i < 4; i++)
      #pragma unroll
      for (int j = 0; j < 4; j++)
        #pragma unroll
        for (int r = 0; r < 4; r++) {
          int gm = mt * 128 + wr * 64 + i * 16 + q4 + r;
          int gd = nt * 128 + wc * 64 + j * 16 + rl;
          size_t off = (size_t)gm * D_ + gd;
          op[off] = st[off] + SCALE_ * acc[i][j][r];
        }
  } else {
    // ---- zero-fill strictly-upper scores tiles
    static const int ZI[6] = {0,0,0,1,1,2};
    static const int ZJ[6] = {1,2,3,2,3,3};
    const int idx = blk - (NB_SC + NB_OP + NB_NS);
    const int head = idx / 6, ti = ZI[idx % 6], tj = ZJ[idx % 6];
    unsigned short* op = Sc + (size_t)head * T_ * T_;
    const uint4 z = make_uint4(0u, 0u, 0u, 0u);
    #pragma unroll
    for (int v = 0; v < 8; v++) {
      int e = v * 256 + t;
      int r = e >> 4, c = (e & 15) * 8;
      *(uint4*)(op + (size_t)(ti * 128 + r) * T_ + tj * 128 + c) = z;
    }
  }
}

// ---------------- Kernel 3: out += Sc @ V ----------------
__global__ __launch_bounds__(256) void final_kernel(
    const unsigned short* __restrict__ Sc, const float* __restrict__ V,
    float* __restrict__ Out)
{
  __shared__ unsigned short as[128 * 32];
  __shared__ unsigned short bs[128 * 40];
  const int blk = blockIdx.x, t = threadIdx.x;
  const int lane = t & 63, w = t >> 6, wr = w >> 1, wc = w & 1;
  const int q4 = (lane >> 4) * 4, rl = lane & 15;
  const int head = blk >> 3, mt = (blk & 7) >> 1, nt = blk & 1;
  const unsigned short* A = Sc + (size_t)head * T_ * T_ + (size_t)mt * 128 * T_;
  const float* Bp = V + (size_t)(head >> 2) * T_ * D_ + nt * 128;
  f32x4 acc[4][4];
  #pragma unroll
  for (int i = 0; i < 4; i++)
    #pragma unroll
    for (int j = 0; j < 4; j++) acc[i][j] = (f32x4){0.f, 0.f, 0.f, 0.f};
  for (int k0 = 0; k0 < T_; k0 += 32) {
    stage_direct(A + k0, T_, as, t);
    stage_trans_f32(Bp + (size_t)k0 * D_, D_, bs, t);
    __syncthreads();
    mfma_step(as, 32, bs, 40, wr, wc, lane, acc);
    __syncthreads();
  }
  float* op = Out + (size_t)head * T_ * D_;
  #pragma unroll
  for (int i = 0; i < 4; i++)
    #pragma unroll
    for (int j = 0; j < 4; j++)
      #pragma unroll
      for (int r = 0; r < 4; r++) {
        int gi = mt * 128 + wr * 64 + i * 16 + q4 + r;
        int gj = nt * 128 + wc * 64 + j * 16 + rl;
        size_t off = (size_t)gi * D_ + gj;
        op[off] = op[off] + acc[i][j][r];     // adds onto QR@state partial from mega
      }
}

extern "C" void kernel_launch(void* const* d_in, const int* in_sizes, int n_in,
                              void* d_out, int out_size, void* d_ws, size_t ws_size,
                              hipStream_t stream) {
  const float* Q     = (const float*)d_in[0];
  const float* V     = (const float*)d_in[1];
  const float* state = (const float*)d_in[2];
  const float* Cos   = (const float*)d_in[3];
  const float* Sin   = (const float*)d_in[4];
  float* out = (float*)d_out;

  // ws: QR bf16 (128 MiB) | Sc bf16 (8 MiB)  -- same footprint as round 1
  unsigned short* QR = (unsigned short*)d_ws;
  unsigned short* Sc = QR + (size_t)NHEAD * T_ * N_;

  rope_kernel<<<dim3(32768), dim3(256), 0, stream>>>(Q, Cos, Sin, QR);
  mega_kernel<<<dim3(NB_SC + NB_OP + NB_NS + 96), dim3(256), 0, stream>>>(QR, V, state, Sc, out);
  final_kernel<<<dim3(128), dim3(256), 0, stream>>>(Sc, V, out);
}

// Round 3
// 796.599 us; speedup vs baseline: 1.3492x; 1.0857x over previous
//
#include <hip/hip_runtime.h>
#include <stdint.h>

#define T_ 512
#define D_ 256
#define N_ 8192
#define NHEAD 16
#define SCALE_ 0.011048543456039806f   // 8192^-0.5
#define INV2PI 0.15915493667125702f

typedef __attribute__((ext_vector_type(8))) short bf16x8;
typedef __attribute__((ext_vector_type(4))) float f32x4;

__device__ __forceinline__ unsigned short f2bf(float x) {
  union { float f; unsigned u; } v; v.f = x;
  unsigned r = v.u + 0x7fffu + ((v.u >> 16) & 1u);   // RNE
  return (unsigned short)(r >> 16);
}

__device__ __forceinline__ void async16(const void* g, void* l) {
  __builtin_amdgcn_global_load_lds(
      (const __attribute__((address_space(1))) unsigned int*)g,
      (__attribute__((address_space(3))) unsigned int*)l,
      16, 0, 0);
}

// ---- swizzled direct staging: 128x32 bf16 tile, row-major source.
// LDS layout [128][32] linear (DMA requires), but LDS block b of row r holds
// GLOBAL block b ^ ((r>>1)&3). Fragment reads XOR-compensate -> conflict-free.
__device__ __forceinline__ void stage_direct(const unsigned short* __restrict__ g,
                                             int ld, unsigned short* lds, int t) {
  const int row = t >> 2, b = t & 3;
  const int g1 = (b ^ ((row >> 1) & 3)) * 8;
  async16(g + (size_t)row * ld + g1, lds + row * 32 + b * 8);
  const int row2 = row + 64;
  const int g2 = (b ^ ((row2 >> 1) & 3)) * 8;
  async16(g + (size_t)row2 * ld + g2, lds + row2 * 32 + b * 8);
}

// ---- transpose staging into padded [128][40] layout (ds_write path, pad ok)
__device__ __forceinline__ void stage_trans_bf16(const unsigned short* __restrict__ g,
                                                 int ld, unsigned short* lds, int t) {
  const int mn = t & 127, ks = (t >> 7) * 16;
  __attribute__((aligned(16))) unsigned short u[16];
  #pragma unroll
  for (int i = 0; i < 16; i++) u[i] = g[(size_t)(ks + i) * ld + mn];
  *(uint4*)(lds + mn * 40 + ks)     = *(const uint4*)u;
  *(uint4*)(lds + mn * 40 + ks + 8) = *(const uint4*)(u + 8);
}

__device__ __forceinline__ void stage_trans_f32(const float* __restrict__ g,
                                                int ld, unsigned short* lds, int t) {
  const int mn = t & 127, ks = (t >> 7) * 16;
  float f[16];
  #pragma unroll
  for (int i = 0; i < 16; i++) f[i] = g[(size_t)(ks + i) * ld + mn];
  __attribute__((aligned(16))) unsigned short u[16];
  #pragma unroll
  for (int i = 0; i < 16; i++) u[i] = f2bf(f[i]);
  *(uint4*)(lds + mn * 40 + ks)     = *(const uint4*)u;
  *(uint4*)(lds + mn * 40 + ks + 8) = *(const uint4*)(u + 8);
}

// ---- fp32 row-major staging with fused scale + strict-tril mask (scores A operand)
__device__ __forceinline__ void stage_sc(const float* __restrict__ g, int gi0, int gk0,
                                         unsigned short* lds, int t) {
  const int row = t >> 2, c8 = (t & 3) * 8;
  #pragma unroll
  for (int rr = 0; rr < 2; rr++) {
    const int r = row + rr * 64;
    const float* p = g + (size_t)r * T_ + c8;
    float4 x = *(const float4*)p, y = *(const float4*)(p + 4);
    float f[8] = {x.x, x.y, x.z, x.w, y.x, y.y, y.z, y.w};
    const int gi = gi0 + r;
    __attribute__((aligned(16))) unsigned short u[8];
    #pragma unroll
    for (int e = 0; e < 8; e++) {
      float v = ((gk0 + c8 + e) < gi) ? f[e] * SCALE_ : 0.f;
      u[e] = f2bf(v);
    }
    *(uint4*)(lds + r * 40 + c8) = *(const uint4*)u;
  }
}

// One BK=32 step: wave (wr,wc) computes 64x64 of the 128x128 C tile.
// SWA/SWB: operand uses swizzled-[128][32] layout (else padded-[128][40]).
template<bool SWA, bool SWB>
__device__ __forceinline__ void mfma_step(const unsigned short* as, const unsigned short* bs,
                                          int wr, int wc, int lane, f32x4 acc[4][4]) {
  const int j8 = lane >> 4, rl = lane & 15;
  const int swz = (j8 ^ ((rl >> 1) & 3)) * 8;   // row base %16==0 -> s(row)=(rl>>1)&3
  const int pad = j8 * 8;
  bf16x8 a[4], b[4];
  #pragma unroll
  for (int i = 0; i < 4; i++) {
    int r = wr * 64 + i * 16 + rl;
    a[i] = SWA ? *(const bf16x8*)(as + r * 32 + swz)
               : *(const bf16x8*)(as + r * 40 + pad);
  }
  #pragma unroll
  for (int j = 0; j < 4; j++) {
    int r = wc * 64 + j * 16 + rl;
    b[j] = SWB ? *(const bf16x8*)(bs + r * 32 + swz)
               : *(const bf16x8*)(bs + r * 40 + pad);
  }
  #pragma unroll
  for (int i = 0; i < 4; i++)
    #pragma unroll
    for (int j = 0; j < 4; j++)
      acc[i][j] = __builtin_amdgcn_mfma_f32_16x16x32_bf16(a[i], b[j], acc[i][j], 0, 0, 0);
}

// ---------------- Kernel 1: QR = rope(Q) -> bf16, cos/sin computed inline ----------------
__global__ __launch_bounds__(256) void rope_kernel(
    const float* __restrict__ Q, unsigned short* __restrict__ QR)
{
  size_t i8 = ((size_t)blockIdx.x * 256 + threadIdx.x) * 8;
  const int t = (int)((i8 >> 13) & (T_ - 1));
  const int n = (int)(i8 & (N_ - 1));
  float q[8];
  *(float4*)q       = *(const float4*)(Q + i8);
  *(float4*)(q + 4) = *(const float4*)(Q + i8 + 4);
  const float ft = (float)t;
  __attribute__((aligned(16))) unsigned short u[8];
  #pragma unroll
  for (int p = 0; p < 4; p++) {
    const int h = (n >> 1) + p;                       // floor(idx/2)
    // freq = theta^(-2h/N)/(2pi) = 2^(-h/256) / (2pi); angle = 2pi*frac(t*freq)
    float f = exp2f((float)h * (-1.0f / 256.0f)) * INV2PI;
    float r = ft * f;
    r = r - floorf(r);                                 // phases mod 1
    float c = __builtin_amdgcn_cosf(r);                // v_cos_f32: cos(2*pi*r)
    float s = __builtin_amdgcn_sinf(r);
    float ev = q[2 * p], od = q[2 * p + 1];
    u[2 * p]     = f2bf(ev * c - od * s);
    u[2 * p + 1] = f2bf(od * c + ev * s);
  }
  *(uint4*)(QR + i8) = *(const uint4*)u;
}

// ---------------- Kernel 2 (mega): scores(splitK4) + QR@state(splitK4) + new_state ----------------
#define NB_SC 640          // 160 lower-tri tiles x 4 K-splits (K-chunk 2048)
#define NB_OP 512          // 128 tiles x 4 K-splits
#define NB_NS 2048         // 64 n-tiles x 2 d-tiles x 16 heads, K=512
#define OUT_STATE_OFF ((size_t)NHEAD * T_ * D_)

__global__ __launch_bounds__(256) void mega_kernel(
    const unsigned short* __restrict__ QR, const float* __restrict__ V,
    const float* __restrict__ state, float* __restrict__ ScF,
    float* __restrict__ Out)
{
  __shared__ unsigned short as[128 * 40];
  __shared__ unsigned short bs[128 * 40];
  const int blk = blockIdx.x, t = threadIdx.x;
  const int lane = t & 63, w = t >> 6, wr = w >> 1, wc = w & 1;
  const int q4 = (lane >> 4) * 4, rl = lane & 15;
  f32x4 acc[4][4];
  #pragma unroll
  for (int i = 0; i < 4; i++)
    #pragma unroll
    for (int j = 0; j < 4; j++) acc[i][j] = (f32x4){0.f, 0.f, 0.f, 0.f};

  if (blk < NB_SC) {
    // ---- scores partial: atomicAdd raw QR.QR^T chunk into ScF (scale/mask at consumer)
    static const int TI[10] = {0,1,1,2,2,2,3,3,3,3};
    static const int TJ[10] = {0,0,1,0,1,2,0,1,2,3};
    const int tile = blk >> 2, split = blk & 3;
    const int head = tile / 10, ti = TI[tile % 10], tj = TJ[tile % 10];
    const unsigned short* A  = QR + (size_t)head * T_ * N_ + (size_t)ti * 128 * N_;
    const unsigned short* Bp = QR + (size_t)head * T_ * N_ + (size_t)tj * 128 * N_;
    const int kbeg = split * 2048, kend = kbeg + 2048;
    for (int k0 = kbeg; k0 < kend; k0 += 32) {
      stage_direct(A + k0, N_, as, t);
      stage_direct(Bp + k0, N_, bs, t);
      __syncthreads();
      mfma_step<true, true>(as, bs, wr, wc, lane, acc);
      __syncthreads();
    }
    float* op = ScF + (size_t)head * T_ * T_;
    #pragma unroll
    for (int i = 0; i < 4; i++)
      #pragma unroll
      for (int j = 0; j < 4; j++)
        #pragma unroll
        for (int r = 0; r < 4; r++) {
          int gi = ti * 128 + wr * 64 + i * 16 + q4 + r;
          int gj = tj * 128 + wc * 64 + j * 16 + rl;
          unsafeAtomicAdd(op + (size_t)gi * T_ + gj, acc[i][j][r]);
        }
  } else if (blk < NB_SC + NB_OP) {
    // ---- out partial: QR @ state chunk, atomicAdd into zeroed Out
    const int idx = blk - NB_SC;
    const int tile = idx >> 2, split = idx & 3;
    const int head = tile >> 3, mt = (tile & 7) >> 1, nt = tile & 1;
    const unsigned short* A = QR + (size_t)head * T_ * N_ + (size_t)mt * 128 * N_;
    const float* Bp = state + (size_t)head * N_ * D_ + nt * 128;   // K-major [n][d]
    const int kbeg = split * 2048, kend = kbeg + 2048;
    for (int k0 = kbeg; k0 < kend; k0 += 32) {
      stage_direct(A + k0, N_, as, t);
      stage_trans_f32(Bp + (size_t)k0 * D_, D_, bs, t);
      __syncthreads();
      mfma_step<true, false>(as, bs, wr, wc, lane, acc);
      __syncthreads();
    }
    float* op = Out + (size_t)head * T_ * D_;
    #pragma unroll
    for (int i = 0; i < 4; i++)
      #pragma unroll
      for (int j = 0; j < 4; j++)
        #pragma unroll
        for (int r = 0; r < 4; r++) {
          int gi = mt * 128 + wr * 64 + i * 16 + q4 + r;
          int gj = nt * 128 + wc * 64 + j * 16 + rl;
          unsafeAtomicAdd(op + (size_t)gi * D_ + gj, acc[i][j][r]);
        }
  } else {
    // ---- new_state = state + SCALE * QR^T @ V
    const int idx = blk - (NB_SC + NB_OP);
    const int head = idx >> 7, mt = (idx & 127) >> 1, nt = idx & 1;
    const unsigned short* Asrc = QR + (size_t)head * T_ * N_ + mt * 128;  // K-major [t][n]
    const float* Bp = V + (size_t)(head >> 2) * T_ * D_ + nt * 128;       // K-major [t][d]
    for (int k0 = 0; k0 < T_; k0 += 32) {
      stage_trans_bf16(Asrc + (size_t)k0 * N_, N_, as, t);
      stage_trans_f32(Bp + (size_t)k0 * D_, D_, bs, t);
      __syncthreads();
      mfma_step<false, false>(as, bs, wr, wc, lane, acc);
      __syncthreads();
    }
    const float* st = state + (size_t)head * N_ * D_;
    float* op = Out + OUT_STATE_OFF + (size_t)head * N_ * D_;
    #pragma unroll
    for (int i = 0; i < 4; i++)
      #pragma unroll
      for (int j = 0; j < 4; j++)
        #pragma unroll
        for (int r = 0; r < 4; r++) {
          int gm = mt * 128 + wr * 64 + i * 16 + q4 + r;
          int gd = nt * 128 + wc * 64 + j * 16 + rl;
          size_t off = (size_t)gm * D_ + gd;
          op[off] = st[off] + SCALE_ * acc[i][j][r];
        }
  }
}

// ---------------- Kernel 3: out += mask(ScF)*SCALE @ V  (splitK2, atomicAdd) ----------------
__global__ __launch_bounds__(256) void final_kernel(
    const float* __restrict__ ScF, const float* __restrict__ V,
    float* __restrict__ Out)
{
  __shared__ unsigned short as[128 * 40];
  __shared__ unsigned short bs[128 * 40];
  const int blk = blockIdx.x, t = threadIdx.x;
  const int lane = t & 63, w = t >> 6, wr = w >> 1, wc = w & 1;
  const int q4 = (lane >> 4) * 4, rl = lane & 15;
  const int tile = blk >> 1, split = blk & 1;
  const int head = tile >> 3, mt = (tile & 7) >> 1, nt = tile & 1;
  const float* A = ScF + (size_t)head * T_ * T_ + (size_t)mt * 128 * T_;
  const float* Bp = V + (size_t)(head >> 2) * T_ * D_ + nt * 128;
  f32x4 acc[4][4];
  #pragma unroll
  for (int i = 0; i < 4; i++)
    #pragma unroll
    for (int j = 0; j < 4; j++) acc[i][j] = (f32x4){0.f, 0.f, 0.f, 0.f};
  const int kbeg = split * 256, kend = kbeg + 256;
  for (int k0 = kbeg; k0 < kend; k0 += 32) {
    stage_sc(A + k0, mt * 128, k0, as, t);
    stage_trans_f32(Bp + (size_t)k0 * D_, D_, bs, t);
    __syncthreads();
    mfma_step<false, false>(as, bs, wr, wc, lane, acc);
    __syncthreads();
  }
  float* op = Out + (size_t)head * T_ * D_;
  #pragma unroll
  for (int i = 0; i < 4; i++)
    #pragma unroll
    for (int j = 0; j < 4; j++)
      #pragma unroll
      for (int r = 0; r < 4; r++) {
        int gi = mt * 128 + wr * 64 + i * 16 + q4 + r;
        int gj = nt * 128 + wc * 64 + j * 16 + rl;
        unsafeAtomicAdd(op + (size_t)gi * D_ + gj, acc[i][j][r]);
      }
}

extern "C" void kernel_launch(void* const* d_in, const int* in_sizes, int n_in,
                              void* d_out, int out_size, void* d_ws, size_t ws_size,
                              hipStream_t stream) {
  const float* Q     = (const float*)d_in[0];
  const float* V     = (const float*)d_in[1];
  const float* state = (const float*)d_in[2];
  float* out = (float*)d_out;

  // ws: QR bf16 (128 MiB) | ScF fp32 (16 MiB)
  unsigned short* QR = (unsigned short*)d_ws;
  float* ScF = (float*)((char*)d_ws + (size_t)NHEAD * T_ * N_ * 2);

  hipMemsetAsync(ScF, 0, (size_t)NHEAD * T_ * T_ * 4, stream);
  hipMemsetAsync(out, 0, (size_t)NHEAD * T_ * D_ * 4, stream);
  rope_kernel<<<dim3(32768), dim3(256), 0, stream>>>(Q, QR);
  mega_kernel<<<dim3(NB_SC + NB_OP + NB_NS), dim3(256), 0, stream>>>(QR, V, state, ScF, out);
  final_kernel<<<dim3(256), dim3(256), 0, stream>>>(ScF, V, out);
}